// Round 5
// baseline (620.201 us; speedup 1.0000x reference)
//
#include <hip/hip_runtime.h>
#include <float.h>

#define N_ROWS  32768
#define K_CODES 8192
#define DIM     64
#define KSPLIT  32
#define KPART   (K_CODES / KSPLIT)   // 256 codes per block slab
#define TILEK   64                   // codes per LDS tile (8 KB)
#define NTILES  (KPART / TILEK)      // 4
#define TSTEPS  (TILEK / 16)         // 4 fragment-steps per tile
#define CAP     32
#define DELTA_D 2e-4f

typedef __attribute__((ext_vector_type(8))) short bf16x8;
typedef __attribute__((ext_vector_type(4))) float f32x4;

// ws layout (bytes):
#define WS_PARTIALS 0          // 2048 f    (8 KB)
#define WS_ZSQ      8192       // 32768 f   (128 KB)
#define WS_IDX      139264     // 32768 i   (128 KB)
#define WS_EBF      270336     // 8192*64 bf16 frag-order (1 MB)
#define WS_ZBF      1318912    // 32768*64 bf16 frag-order (4 MB)
#define WS_MAX      5513216    // [32][32768] f (4 MB); reused as cands after vq_thr
#define WS_CANDS    5513216    // 32768*32 i (4 MB) — overlays WS_MAX
#define WS_THR      9707520    // 32768 f   (128 KB)
#define WS_CNT      9838592    // 32768 i   (128 KB)  -> total ~9.5 MB

__device__ __forceinline__ unsigned short f2bf(float f) {
  unsigned u = __float_as_uint(f);
  u = (u + 0x7fffu + ((u >> 16) & 1u)) >> 16;   // RNE, finite inputs
  return (unsigned short)u;
}

__device__ __forceinline__ void gload_lds16(const void* g, void* l) {
  typedef const __attribute__((address_space(1))) unsigned int* gp_t;
  typedef __attribute__((address_space(3))) unsigned int* lp_t;
  __builtin_amdgcn_global_load_lds((gp_t)g, (lp_t)l, 16, 0, 0);
}

#define MFMA16(a, b, c) __builtin_amdgcn_mfma_f32_16x16x32_bf16((a), (b), (c), 0, 0, 0)

// ----------------------------------------------------------------- z_sq ----
// Bit-exact numpy pairwise sum of z*z over 64 elems (validated round 2).
__global__ __launch_bounds__(256) void vq_zsq(const float* __restrict__ z,
                                              float* __restrict__ zsq) {
  const int row = blockIdx.x * 256 + threadIdx.x;
  const float4* z4 = reinterpret_cast<const float4*>(z + (size_t)row * DIM);
  float r[8];
  {
    const float4 v0 = z4[0], v1 = z4[1];
    r[0] = __fmul_rn(v0.x, v0.x); r[1] = __fmul_rn(v0.y, v0.y);
    r[2] = __fmul_rn(v0.z, v0.z); r[3] = __fmul_rn(v0.w, v0.w);
    r[4] = __fmul_rn(v1.x, v1.x); r[5] = __fmul_rn(v1.y, v1.y);
    r[6] = __fmul_rn(v1.z, v1.z); r[7] = __fmul_rn(v1.w, v1.w);
  }
#pragma unroll
  for (int i = 1; i < 8; ++i) {
    const float4 v0 = z4[2 * i], v1 = z4[2 * i + 1];
    r[0] = __fadd_rn(r[0], __fmul_rn(v0.x, v0.x));
    r[1] = __fadd_rn(r[1], __fmul_rn(v0.y, v0.y));
    r[2] = __fadd_rn(r[2], __fmul_rn(v0.z, v0.z));
    r[3] = __fadd_rn(r[3], __fmul_rn(v0.w, v0.w));
    r[4] = __fadd_rn(r[4], __fmul_rn(v1.x, v1.x));
    r[5] = __fadd_rn(r[5], __fmul_rn(v1.y, v1.y));
    r[6] = __fadd_rn(r[6], __fmul_rn(v1.z, v1.z));
    r[7] = __fadd_rn(r[7], __fmul_rn(v1.w, v1.w));
  }
  zsq[row] = __fadd_rn(
      __fadd_rn(__fadd_rn(r[0], r[1]), __fadd_rn(r[2], r[3])),
      __fadd_rn(__fadd_rn(r[4], r[5]), __fadd_rn(r[6], r[7])));
}

// ------------------------------------------------- cvt to fragment order ----
// chunk c (8 bf16 = 16B): l=c&63, h=(c>>6)&1, t=c>>7
//   dst[c] = src[idx = t*16 + (l&15)][d = h*32 + (l>>4)*8 .. +8]
// Exactly the per-lane A/B fragment of mfma_f32_16x16x32_bf16 (validated r3).
__global__ __launch_bounds__(256) void vq_cvt_frag(
    const float* __restrict__ src, unsigned short* __restrict__ dst) {
  const int c = blockIdx.x * 256 + threadIdx.x;
  const int l = c & 63, h = (c >> 6) & 1, t = c >> 7;
  const float* p =
      src + (size_t)(t * 16 + (l & 15)) * DIM + h * 32 + ((l >> 4) << 3);
  const float4 f0 = *reinterpret_cast<const float4*>(p);
  const float4 f1 = *reinterpret_cast<const float4*>(p + 4);
  ushort4 o0, o1;
  o0.x = f2bf(f0.x); o0.y = f2bf(f0.y); o0.z = f2bf(f0.z); o0.w = f2bf(f0.w);
  o1.x = f2bf(f1.x); o1.y = f2bf(f1.y); o1.z = f2bf(f1.z); o1.w = f2bf(f1.w);
  reinterpret_cast<ushort4*>(dst)[2 * c] = o0;
  reinterpret_cast<ushort4*>(dst)[2 * c + 1] = o1;
}

// --------------------------------------------- pass A: per-row max(dot~) ----
// Block: 4 waves x 128 rows = 512 rows, one k-slab of 256 codes.
// Grid 2048 blocks -> 8/CU available, 6 resident (launch_bounds).
__global__ __launch_bounds__(256, 6) void vq_sweep_max(
    const unsigned short* __restrict__ zbf,
    const unsigned short* __restrict__ ebf, float* __restrict__ wsmax) {
  __shared__ f32x4 lds4[1024];   // 16 KB = 2 x 8 KB tiles
  char* lds = (char*)lds4;
  const int tid = threadIdx.x;
  const int wid = tid >> 6, l = tid & 63;
  const int rowblk = blockIdx.x & 63, kp = blockIdx.x >> 6;
  const int waveRow = rowblk * 512 + wid * 128;
  const int baseTile = waveRow >> 4;

  bf16x8 bz[8][2];
#pragma unroll
  for (int rt = 0; rt < 8; ++rt)
#pragma unroll
    for (int h = 0; h < 2; ++h)
      bz[rt][h] = *reinterpret_cast<const bf16x8*>(
          zbf + ((size_t)((baseTile + rt) * 2 + h) * 64 + l) * 8);

  const char* slab = (const char*)ebf + (size_t)kp * (KPART * DIM * 2);
#pragma unroll
  for (int c = 0; c < 2; ++c)
    gload_lds16(slab + (wid * 2 + c) * 1024 + l * 16,
                lds + (wid * 2 + c) * 1024);
  __syncthreads();

  const f32x4 zero = {0.f, 0.f, 0.f, 0.f};
  f32x4 m[8];
#pragma unroll
  for (int rt = 0; rt < 8; ++rt)
    m[rt] = (f32x4){-FLT_MAX, -FLT_MAX, -FLT_MAX, -FLT_MAX};

  for (int tk = 0; tk < NTILES; ++tk) {
    char* cur = lds + (tk & 1) * 8192;
    if (tk + 1 < NTILES) {
      char* nxt = lds + ((tk + 1) & 1) * 8192;
      const char* src = slab + (size_t)(tk + 1) * 8192;
#pragma unroll
      for (int c = 0; c < 2; ++c)
        gload_lds16(src + (wid * 2 + c) * 1024 + l * 16,
                    nxt + (wid * 2 + c) * 1024);
    }
#pragma unroll
    for (int s = 0; s < TSTEPS; ++s) {
      const bf16x8 a0 = *reinterpret_cast<const bf16x8*>(cur + s * 2048 + l * 16);
      const bf16x8 a1 =
          *reinterpret_cast<const bf16x8*>(cur + s * 2048 + 1024 + l * 16);
#pragma unroll
      for (int rt = 0; rt < 8; ++rt) {
        f32x4 t = MFMA16(a0, bz[rt][0], zero);
        t = MFMA16(a1, bz[rt][1], t);
        m[rt][0] = fmaxf(m[rt][0], t[0]);
        m[rt][1] = fmaxf(m[rt][1], t[1]);
        m[rt][2] = fmaxf(m[rt][2], t[2]);
        m[rt][3] = fmaxf(m[rt][3], t[3]);
      }
    }
    __syncthreads();
  }

#pragma unroll
  for (int rt = 0; rt < 8; ++rt) {
    float mm = fmaxf(fmaxf(m[rt][0], m[rt][1]), fmaxf(m[rt][2], m[rt][3]));
    mm = fmaxf(mm, __shfl_xor(mm, 16, 64));
    mm = fmaxf(mm, __shfl_xor(mm, 32, 64));
    if (l < 16)   // [kp][row] layout: coalesced 64B chunks
      wsmax[(size_t)kp * N_ROWS + waveRow + rt * 16 + l] = mm;
  }
}

// -------------------------------------- reduce per-slab maxima to thr ----
__global__ __launch_bounds__(256) void vq_thr(const float* __restrict__ wsmax,
                                              float* __restrict__ thr) {
  const int row = blockIdx.x * 256 + threadIdx.x;
  float m = -FLT_MAX;
#pragma unroll
  for (int p = 0; p < KSPLIT; ++p)
    m = fmaxf(m, wsmax[(size_t)p * N_ROWS + row]);
  thr[row] = m - DELTA_D;
}

// ----------------------------------- pass B: collect near-max candidates ----
__global__ __launch_bounds__(256, 6) void vq_sweep_collect(
    const unsigned short* __restrict__ zbf,
    const unsigned short* __restrict__ ebf, const float* __restrict__ thrbuf,
    int* __restrict__ cnt, int* __restrict__ cands) {
  __shared__ f32x4 lds4[1024];
  char* lds = (char*)lds4;
  const int tid = threadIdx.x;
  const int wid = tid >> 6, l = tid & 63;
  const int l15 = l & 15, lg = l >> 4;
  const int rowblk = blockIdx.x & 63, kp = blockIdx.x >> 6;
  const int kb = kp * KPART;
  const int waveRow = rowblk * 512 + wid * 128;
  const int baseTile = waveRow >> 4;

  bf16x8 bz[8][2];
#pragma unroll
  for (int rt = 0; rt < 8; ++rt)
#pragma unroll
    for (int h = 0; h < 2; ++h)
      bz[rt][h] = *reinterpret_cast<const bf16x8*>(
          zbf + ((size_t)((baseTile + rt) * 2 + h) * 64 + l) * 8);

  float thr[8];
#pragma unroll
  for (int rt = 0; rt < 8; ++rt)
    thr[rt] = thrbuf[waveRow + rt * 16 + l15];

  const char* slab = (const char*)ebf + (size_t)kp * (KPART * DIM * 2);
#pragma unroll
  for (int c = 0; c < 2; ++c)
    gload_lds16(slab + (wid * 2 + c) * 1024 + l * 16,
                lds + (wid * 2 + c) * 1024);
  __syncthreads();

  const f32x4 zero = {0.f, 0.f, 0.f, 0.f};

  for (int tk = 0; tk < NTILES; ++tk) {
    char* cur = lds + (tk & 1) * 8192;
    if (tk + 1 < NTILES) {
      char* nxt = lds + ((tk + 1) & 1) * 8192;
      const char* src = slab + (size_t)(tk + 1) * 8192;
#pragma unroll
      for (int c = 0; c < 2; ++c)
        gload_lds16(src + (wid * 2 + c) * 1024 + l * 16,
                    nxt + (wid * 2 + c) * 1024);
    }
#pragma unroll
    for (int s = 0; s < TSTEPS; ++s) {
      const bf16x8 a0 = *reinterpret_cast<const bf16x8*>(cur + s * 2048 + l * 16);
      const bf16x8 a1 =
          *reinterpret_cast<const bf16x8*>(cur + s * 2048 + 1024 + l * 16);
#pragma unroll
      for (int rt = 0; rt < 8; ++rt) {
        f32x4 t = MFMA16(a0, bz[rt][0], zero);
        t = MFMA16(a1, bz[rt][1], t);   // bit-identical to pass A
        if (t[0] >= thr[rt] || t[1] >= thr[rt] || t[2] >= thr[rt] ||
            t[3] >= thr[rt]) {          // rare
          const int row = waveRow + rt * 16 + l15;
          const int kbase = kb + tk * TILEK + s * 16 + lg * 4;
#pragma unroll
          for (int i = 0; i < 4; ++i)
            if (t[i] >= thr[rt]) {
              const int pos = atomicAdd(&cnt[row], 1);
              if (pos < CAP) cands[(size_t)row * CAP + pos] = kbase + i;
            }
        }
      }
    }
    __syncthreads();
  }
}

// ------------------------- resolve: exact ref chain on candidates only ----
__global__ __launch_bounds__(256) void vq_resolve(
    const float* __restrict__ z, const float* __restrict__ e,
    const float* __restrict__ zsq, const int* __restrict__ cnt,
    const int* __restrict__ cands, int* __restrict__ oidx,
    float* __restrict__ oidxf) {
  const int row = blockIdx.x * 256 + threadIdx.x;
  float zr[DIM];
#pragma unroll
  for (int t = 0; t < DIM / 4; ++t) {
    const float4 v = reinterpret_cast<const float4*>(z + (size_t)row * DIM)[t];
    zr[4 * t + 0] = v.x; zr[4 * t + 1] = v.y;
    zr[4 * t + 2] = v.z; zr[4 * t + 3] = v.w;
  }
  const float zq = zsq[row];
  int c = cnt[row];
  if (c > CAP) c = CAP;
  float bs = FLT_MAX;
  int bk = 0;
  for (int j = 0; j < c; ++j) {
    const int k = cands[(size_t)row * CAP + j];
    const float* er = e + (size_t)k * DIM;
    float dot = 0.f;
#pragma unroll
    for (int d = 0; d < DIM; ++d) dot = fmaf(zr[d], er[d], dot);
    const float s = fmaf(-2.f, dot, zq);   // bit-exact vs reference (round 2)
    if (s < bs || (s == bs && k < bk)) { bs = s; bk = k; }
  }
  oidx[row] = bk;
  oidxf[row] = (float)bk;
}

// -------------------------------------------------------- gather + loss ----
__global__ __launch_bounds__(256) void vq_gather_loss(
    const float* __restrict__ z, const float* __restrict__ e,
    const int* __restrict__ idx, float* __restrict__ qout,
    float* __restrict__ partials) {
  const int tid = threadIdx.x;
  const int rl = tid >> 4;
  const int t = tid & 15;
  const int row = blockIdx.x * 16 + rl;
  const int id = idx[row];
  const float4 qv =
      *reinterpret_cast<const float4*>(e + (size_t)id * DIM + 4 * t);
  const float4 zv =
      *reinterpret_cast<const float4*>(z + (size_t)row * DIM + 4 * t);
  *reinterpret_cast<float4*>(qout + (size_t)row * DIM + 4 * t) = qv;
  const float dx = zv.x - qv.x, dy = zv.y - qv.y;
  const float dz = zv.z - qv.z, dw = zv.w - qv.w;
  float s = dx * dx + dy * dy + dz * dz + dw * dw;

  __shared__ float red[256];
  red[tid] = s;
  __syncthreads();
  for (int off = 128; off > 0; off >>= 1) {
    if (tid < off) red[tid] += red[tid + off];
    __syncthreads();
  }
  if (tid == 0) partials[blockIdx.x] = red[0];
}

// ------------------------------------------------------------ finalize ----
__global__ __launch_bounds__(256) void vq_finalize(
    const float* __restrict__ partials, float* __restrict__ loss_out) {
  const int tid = threadIdx.x;
  float s = 0.f;
#pragma unroll
  for (int j = 0; j < 8; ++j) s += partials[tid + 256 * j];
  __shared__ float red[256];
  red[tid] = s;
  __syncthreads();
  for (int off = 128; off > 0; off >>= 1) {
    if (tid < off) red[tid] += red[tid + off];
    __syncthreads();
  }
  if (tid == 0) {
    const float loss = red[0] / (float)(N_ROWS * DIM);
    loss_out[0] = loss;
    loss_out[1] = loss;
  }
}

extern "C" void kernel_launch(void* const* d_in, const int* in_sizes, int n_in,
                              void* d_out, int out_size, void* d_ws,
                              size_t ws_size, hipStream_t stream) {
  const float* z = (const float*)d_in[0];   // [32768, 64]
  const float* e = (const float*)d_in[1];   // [8192, 64]
  float* out = (float*)d_out;
  float* qout = out;
  float* loss_out = out + (size_t)N_ROWS * DIM;
  float* idxf_out = loss_out + 2;

  char* ws = (char*)d_ws;
  float* partials = (float*)(ws + WS_PARTIALS);
  float* zsq = (float*)(ws + WS_ZSQ);
  int* idx = (int*)(ws + WS_IDX);
  unsigned short* ebf = (unsigned short*)(ws + WS_EBF);
  unsigned short* zbf = (unsigned short*)(ws + WS_ZBF);
  float* wsmax = (float*)(ws + WS_MAX);
  float* thr = (float*)(ws + WS_THR);
  int* cnt = (int*)(ws + WS_CNT);
  int* cands = (int*)(ws + WS_CANDS);   // overlays wsmax (dead after vq_thr)

  hipMemsetAsync(cnt, 0, N_ROWS * sizeof(int), stream);
  vq_zsq<<<N_ROWS / 256, 256, 0, stream>>>(z, zsq);
  vq_cvt_frag<<<(K_CODES * DIM / 8) / 256, 256, 0, stream>>>(e, ebf);
  vq_cvt_frag<<<(N_ROWS * DIM / 8) / 256, 256, 0, stream>>>(z, zbf);
  vq_sweep_max<<<64 * KSPLIT, 256, 0, stream>>>(zbf, ebf, wsmax);
  vq_thr<<<N_ROWS / 256, 256, 0, stream>>>(wsmax, thr);
  vq_sweep_collect<<<64 * KSPLIT, 256, 0, stream>>>(zbf, ebf, thr, cnt, cands);
  vq_resolve<<<N_ROWS / 256, 256, 0, stream>>>(z, e, zsq, cnt, cands, idx,
                                               idxf_out);
  vq_gather_loss<<<N_ROWS / 16, 256, 0, stream>>>(z, e, idx, qout, partials);
  vq_finalize<<<1, 256, 0, stream>>>(partials, loss_out);
}

// Round 6
// 180.061 us; speedup vs baseline: 3.4444x; 3.4444x over previous
//
#include <hip/hip_runtime.h>
#include <float.h>

#define N_ROWS  32768
#define K_CODES 8192
#define DIM     64
#define KSPLIT  32
#define KPART   (K_CODES / KSPLIT)   // 256 codes per block slab
#define TILEK   64                   // codes per LDS tile (8 KB)
#define NTILES  (KPART / TILEK)      // 4
#define TSTEPS  (TILEK / 16)         // 4 fragment-steps per tile
#define CAP     32
#define DELTA_D 2e-4f

typedef __attribute__((ext_vector_type(8))) short bf16x8;
typedef __attribute__((ext_vector_type(4))) float f32x4;

// ws layout (bytes):
#define WS_PARTIALS 0          // 2048 f    (8 KB)
#define WS_ZSQ      8192       // 32768 f   (128 KB)
#define WS_IDX      139264     // 32768 i   (128 KB)
#define WS_EBF      270336     // 8192*64 bf16 frag-order (1 MB)
#define WS_ZBF      1318912    // 32768*64 bf16 frag-order (4 MB)
#define WS_MAX      5513216    // [32][32768] f (4 MB); reused as cands after vq_thr
#define WS_CANDS    5513216    // 32768*32 i (4 MB) — overlays WS_MAX
#define WS_THR      9707520    // 32768 f   (128 KB)
#define WS_CNT      9838592    // 32768 i   (128 KB)  -> total ~9.5 MB

__device__ __forceinline__ unsigned short f2bf(float f) {
  unsigned u = __float_as_uint(f);
  u = (u + 0x7fffu + ((u >> 16) & 1u)) >> 16;   // RNE, finite inputs
  return (unsigned short)u;
}

__device__ __forceinline__ void gload_lds16(const void* g, void* l) {
  typedef const __attribute__((address_space(1))) unsigned int* gp_t;
  typedef __attribute__((address_space(3))) unsigned int* lp_t;
  __builtin_amdgcn_global_load_lds((gp_t)g, (lp_t)l, 16, 0, 0);
}

#define MFMA16(a, b, c) __builtin_amdgcn_mfma_f32_16x16x32_bf16((a), (b), (c), 0, 0, 0)

// ----------------------------------------------------------------- z_sq ----
// Bit-exact numpy pairwise sum of z*z over 64 elems (validated round 2).
__global__ __launch_bounds__(256) void vq_zsq(const float* __restrict__ z,
                                              float* __restrict__ zsq) {
  const int row = blockIdx.x * 256 + threadIdx.x;
  const float4* z4 = reinterpret_cast<const float4*>(z + (size_t)row * DIM);
  float r[8];
  {
    const float4 v0 = z4[0], v1 = z4[1];
    r[0] = __fmul_rn(v0.x, v0.x); r[1] = __fmul_rn(v0.y, v0.y);
    r[2] = __fmul_rn(v0.z, v0.z); r[3] = __fmul_rn(v0.w, v0.w);
    r[4] = __fmul_rn(v1.x, v1.x); r[5] = __fmul_rn(v1.y, v1.y);
    r[6] = __fmul_rn(v1.z, v1.z); r[7] = __fmul_rn(v1.w, v1.w);
  }
#pragma unroll
  for (int i = 1; i < 8; ++i) {
    const float4 v0 = z4[2 * i], v1 = z4[2 * i + 1];
    r[0] = __fadd_rn(r[0], __fmul_rn(v0.x, v0.x));
    r[1] = __fadd_rn(r[1], __fmul_rn(v0.y, v0.y));
    r[2] = __fadd_rn(r[2], __fmul_rn(v0.z, v0.z));
    r[3] = __fadd_rn(r[3], __fmul_rn(v0.w, v0.w));
    r[4] = __fadd_rn(r[4], __fmul_rn(v1.x, v1.x));
    r[5] = __fadd_rn(r[5], __fmul_rn(v1.y, v1.y));
    r[6] = __fadd_rn(r[6], __fmul_rn(v1.z, v1.z));
    r[7] = __fadd_rn(r[7], __fmul_rn(v1.w, v1.w));
  }
  zsq[row] = __fadd_rn(
      __fadd_rn(__fadd_rn(r[0], r[1]), __fadd_rn(r[2], r[3])),
      __fadd_rn(__fadd_rn(r[4], r[5]), __fadd_rn(r[6], r[7])));
}

// ------------------------------------------------- cvt to fragment order ----
// chunk c (8 bf16 = 16B): l=c&63, h=(c>>6)&1, t=c>>7
//   dst[c] = src[idx = t*16 + (l&15)][d = h*32 + (l>>4)*8 .. +8]
// Exactly the per-lane A/B fragment of mfma_f32_16x16x32_bf16 (validated r3).
__global__ __launch_bounds__(256) void vq_cvt_frag(
    const float* __restrict__ src, unsigned short* __restrict__ dst) {
  const int c = blockIdx.x * 256 + threadIdx.x;
  const int l = c & 63, h = (c >> 6) & 1, t = c >> 7;
  const float* p =
      src + (size_t)(t * 16 + (l & 15)) * DIM + h * 32 + ((l >> 4) << 3);
  const float4 f0 = *reinterpret_cast<const float4*>(p);
  const float4 f1 = *reinterpret_cast<const float4*>(p + 4);
  ushort4 o0, o1;
  o0.x = f2bf(f0.x); o0.y = f2bf(f0.y); o0.z = f2bf(f0.z); o0.w = f2bf(f0.w);
  o1.x = f2bf(f1.x); o1.y = f2bf(f1.y); o1.z = f2bf(f1.z); o1.w = f2bf(f1.w);
  reinterpret_cast<ushort4*>(dst)[2 * c] = o0;
  reinterpret_cast<ushort4*>(dst)[2 * c + 1] = o1;
}

// --------------------------------------------- pass A: per-row max(dot~) ----
// Block: 4 waves x 128 rows = 512 rows, one k-slab of 256 codes.
// Grid 2048 blocks. VGPR budget ~70 live -> launch_bounds(256,4) (cap 128,
// NO spill — round-5 lesson: (256,6) capped to 40 VGPR and spilled bz/m
// to scratch = 765 MB HBM r/w storm).
__global__ __launch_bounds__(256, 4) void vq_sweep_max(
    const unsigned short* __restrict__ zbf,
    const unsigned short* __restrict__ ebf, float* __restrict__ wsmax) {
  __shared__ f32x4 lds4[1024];   // 16 KB = 2 x 8 KB tiles
  char* lds = (char*)lds4;
  const int tid = threadIdx.x;
  const int wid = tid >> 6, l = tid & 63;
  const int rowblk = blockIdx.x & 63, kp = blockIdx.x >> 6;
  const int waveRow = rowblk * 512 + wid * 128;
  const int baseTile = waveRow >> 4;

  bf16x8 bz[8][2];
#pragma unroll
  for (int rt = 0; rt < 8; ++rt)
#pragma unroll
    for (int h = 0; h < 2; ++h)
      bz[rt][h] = *reinterpret_cast<const bf16x8*>(
          zbf + ((size_t)((baseTile + rt) * 2 + h) * 64 + l) * 8);

  const char* slab = (const char*)ebf + (size_t)kp * (KPART * DIM * 2);
#pragma unroll
  for (int c = 0; c < 2; ++c)
    gload_lds16(slab + (wid * 2 + c) * 1024 + l * 16,
                lds + (wid * 2 + c) * 1024);
  __syncthreads();

  const f32x4 zero = {0.f, 0.f, 0.f, 0.f};
  float m[8];   // scalar running max per row-tile (8 VGPR, not 32)
#pragma unroll
  for (int rt = 0; rt < 8; ++rt) m[rt] = -FLT_MAX;

  for (int tk = 0; tk < NTILES; ++tk) {
    char* cur = lds + (tk & 1) * 8192;
    if (tk + 1 < NTILES) {
      char* nxt = lds + ((tk + 1) & 1) * 8192;
      const char* src = slab + (size_t)(tk + 1) * 8192;
#pragma unroll
      for (int c = 0; c < 2; ++c)
        gload_lds16(src + (wid * 2 + c) * 1024 + l * 16,
                    nxt + (wid * 2 + c) * 1024);
    }
#pragma unroll
    for (int s = 0; s < TSTEPS; ++s) {
      const bf16x8 a0 = *reinterpret_cast<const bf16x8*>(cur + s * 2048 + l * 16);
      const bf16x8 a1 =
          *reinterpret_cast<const bf16x8*>(cur + s * 2048 + 1024 + l * 16);
#pragma unroll
      for (int rt = 0; rt < 8; ++rt) {
        f32x4 t = MFMA16(a0, bz[rt][0], zero);
        t = MFMA16(a1, bz[rt][1], t);
        m[rt] = fmaxf(m[rt],
                      fmaxf(fmaxf(t[0], t[1]), fmaxf(t[2], t[3])));
      }
    }
    __syncthreads();
  }

#pragma unroll
  for (int rt = 0; rt < 8; ++rt) {
    float mm = m[rt];
    mm = fmaxf(mm, __shfl_xor(mm, 16, 64));
    mm = fmaxf(mm, __shfl_xor(mm, 32, 64));
    if (l < 16)   // [kp][row] layout: coalesced 64B chunks
      wsmax[(size_t)kp * N_ROWS + waveRow + rt * 16 + l] = mm;
  }
}

// -------------------------------------- reduce per-slab maxima to thr ----
__global__ __launch_bounds__(256) void vq_thr(const float* __restrict__ wsmax,
                                              float* __restrict__ thr) {
  const int row = blockIdx.x * 256 + threadIdx.x;
  float m = -FLT_MAX;
#pragma unroll
  for (int p = 0; p < KSPLIT; ++p)
    m = fmaxf(m, wsmax[(size_t)p * N_ROWS + row]);
  thr[row] = m - DELTA_D;
}

// ----------------------------------- pass B: collect near-max candidates ----
__global__ __launch_bounds__(256, 4) void vq_sweep_collect(
    const unsigned short* __restrict__ zbf,
    const unsigned short* __restrict__ ebf, const float* __restrict__ thrbuf,
    int* __restrict__ cnt, int* __restrict__ cands) {
  __shared__ f32x4 lds4[1024];
  char* lds = (char*)lds4;
  const int tid = threadIdx.x;
  const int wid = tid >> 6, l = tid & 63;
  const int l15 = l & 15, lg = l >> 4;
  const int rowblk = blockIdx.x & 63, kp = blockIdx.x >> 6;
  const int kb = kp * KPART;
  const int waveRow = rowblk * 512 + wid * 128;
  const int baseTile = waveRow >> 4;

  bf16x8 bz[8][2];
#pragma unroll
  for (int rt = 0; rt < 8; ++rt)
#pragma unroll
    for (int h = 0; h < 2; ++h)
      bz[rt][h] = *reinterpret_cast<const bf16x8*>(
          zbf + ((size_t)((baseTile + rt) * 2 + h) * 64 + l) * 8);

  float thr[8];
#pragma unroll
  for (int rt = 0; rt < 8; ++rt)
    thr[rt] = thrbuf[waveRow + rt * 16 + l15];

  const char* slab = (const char*)ebf + (size_t)kp * (KPART * DIM * 2);
#pragma unroll
  for (int c = 0; c < 2; ++c)
    gload_lds16(slab + (wid * 2 + c) * 1024 + l * 16,
                lds + (wid * 2 + c) * 1024);
  __syncthreads();

  const f32x4 zero = {0.f, 0.f, 0.f, 0.f};

  for (int tk = 0; tk < NTILES; ++tk) {
    char* cur = lds + (tk & 1) * 8192;
    if (tk + 1 < NTILES) {
      char* nxt = lds + ((tk + 1) & 1) * 8192;
      const char* src = slab + (size_t)(tk + 1) * 8192;
#pragma unroll
      for (int c = 0; c < 2; ++c)
        gload_lds16(src + (wid * 2 + c) * 1024 + l * 16,
                    nxt + (wid * 2 + c) * 1024);
    }
#pragma unroll
    for (int s = 0; s < TSTEPS; ++s) {
      const bf16x8 a0 = *reinterpret_cast<const bf16x8*>(cur + s * 2048 + l * 16);
      const bf16x8 a1 =
          *reinterpret_cast<const bf16x8*>(cur + s * 2048 + 1024 + l * 16);
#pragma unroll
      for (int rt = 0; rt < 8; ++rt) {
        f32x4 t = MFMA16(a0, bz[rt][0], zero);
        t = MFMA16(a1, bz[rt][1], t);   // bit-identical to pass A
        if (t[0] >= thr[rt] || t[1] >= thr[rt] || t[2] >= thr[rt] ||
            t[3] >= thr[rt]) {          // rare
          const int row = waveRow + rt * 16 + l15;
          const int kbase = kb + tk * TILEK + s * 16 + lg * 4;
#pragma unroll
          for (int i = 0; i < 4; ++i)
            if (t[i] >= thr[rt]) {
              const int pos = atomicAdd(&cnt[row], 1);
              if (pos < CAP) cands[(size_t)row * CAP + pos] = kbase + i;
            }
        }
      }
    }
    __syncthreads();
  }
}

// ------------------------- resolve: exact ref chain on candidates only ----
__global__ __launch_bounds__(256) void vq_resolve(
    const float* __restrict__ z, const float* __restrict__ e,
    const float* __restrict__ zsq, const int* __restrict__ cnt,
    const int* __restrict__ cands, int* __restrict__ oidx,
    float* __restrict__ oidxf) {
  const int row = blockIdx.x * 256 + threadIdx.x;
  float zr[DIM];
#pragma unroll
  for (int t = 0; t < DIM / 4; ++t) {
    const float4 v = reinterpret_cast<const float4*>(z + (size_t)row * DIM)[t];
    zr[4 * t + 0] = v.x; zr[4 * t + 1] = v.y;
    zr[4 * t + 2] = v.z; zr[4 * t + 3] = v.w;
  }
  const float zq = zsq[row];
  int c = cnt[row];
  if (c > CAP) c = CAP;
  float bs = FLT_MAX;
  int bk = 0;
  for (int j = 0; j < c; ++j) {
    const int k = cands[(size_t)row * CAP + j];
    const float* er = e + (size_t)k * DIM;
    float dot = 0.f;
#pragma unroll
    for (int d = 0; d < DIM; ++d) dot = fmaf(zr[d], er[d], dot);
    const float s = fmaf(-2.f, dot, zq);   // bit-exact vs reference (round 2)
    if (s < bs || (s == bs && k < bk)) { bs = s; bk = k; }
  }
  oidx[row] = bk;
  oidxf[row] = (float)bk;
}

// -------------------------------------------------------- gather + loss ----
__global__ __launch_bounds__(256) void vq_gather_loss(
    const float* __restrict__ z, const float* __restrict__ e,
    const int* __restrict__ idx, float* __restrict__ qout,
    float* __restrict__ partials) {
  const int tid = threadIdx.x;
  const int rl = tid >> 4;
  const int t = tid & 15;
  const int row = blockIdx.x * 16 + rl;
  const int id = idx[row];
  const float4 qv =
      *reinterpret_cast<const float4*>(e + (size_t)id * DIM + 4 * t);
  const float4 zv =
      *reinterpret_cast<const float4*>(z + (size_t)row * DIM + 4 * t);
  *reinterpret_cast<float4*>(qout + (size_t)row * DIM + 4 * t) = qv;
  const float dx = zv.x - qv.x, dy = zv.y - qv.y;
  const float dz = zv.z - qv.z, dw = zv.w - qv.w;
  float s = dx * dx + dy * dy + dz * dz + dw * dw;

  __shared__ float red[256];
  red[tid] = s;
  __syncthreads();
  for (int off = 128; off > 0; off >>= 1) {
    if (tid < off) red[tid] += red[tid + off];
    __syncthreads();
  }
  if (tid == 0) partials[blockIdx.x] = red[0];
}

// ------------------------------------------------------------ finalize ----
__global__ __launch_bounds__(256) void vq_finalize(
    const float* __restrict__ partials, float* __restrict__ loss_out) {
  const int tid = threadIdx.x;
  float s = 0.f;
#pragma unroll
  for (int j = 0; j < 8; ++j) s += partials[tid + 256 * j];
  __shared__ float red[256];
  red[tid] = s;
  __syncthreads();
  for (int off = 128; off > 0; off >>= 1) {
    if (tid < off) red[tid] += red[tid + off];
    __syncthreads();
  }
  if (tid == 0) {
    const float loss = red[0] / (float)(N_ROWS * DIM);
    loss_out[0] = loss;
    loss_out[1] = loss;
  }
}

extern "C" void kernel_launch(void* const* d_in, const int* in_sizes, int n_in,
                              void* d_out, int out_size, void* d_ws,
                              size_t ws_size, hipStream_t stream) {
  const float* z = (const float*)d_in[0];   // [32768, 64]
  const float* e = (const float*)d_in[1];   // [8192, 64]
  float* out = (float*)d_out;
  float* qout = out;
  float* loss_out = out + (size_t)N_ROWS * DIM;
  float* idxf_out = loss_out + 2;

  char* ws = (char*)d_ws;
  float* partials = (float*)(ws + WS_PARTIALS);
  float* zsq = (float*)(ws + WS_ZSQ);
  int* idx = (int*)(ws + WS_IDX);
  unsigned short* ebf = (unsigned short*)(ws + WS_EBF);
  unsigned short* zbf = (unsigned short*)(ws + WS_ZBF);
  float* wsmax = (float*)(ws + WS_MAX);
  float* thr = (float*)(ws + WS_THR);
  int* cnt = (int*)(ws + WS_CNT);
  int* cands = (int*)(ws + WS_CANDS);   // overlays wsmax (dead after vq_thr)

  hipMemsetAsync(cnt, 0, N_ROWS * sizeof(int), stream);
  vq_zsq<<<N_ROWS / 256, 256, 0, stream>>>(z, zsq);
  vq_cvt_frag<<<(K_CODES * DIM / 8) / 256, 256, 0, stream>>>(e, ebf);
  vq_cvt_frag<<<(N_ROWS * DIM / 8) / 256, 256, 0, stream>>>(z, zbf);
  vq_sweep_max<<<64 * KSPLIT, 256, 0, stream>>>(zbf, ebf, wsmax);
  vq_thr<<<N_ROWS / 256, 256, 0, stream>>>(wsmax, thr);
  vq_sweep_collect<<<64 * KSPLIT, 256, 0, stream>>>(zbf, ebf, thr, cnt, cands);
  vq_resolve<<<N_ROWS / 256, 256, 0, stream>>>(z, e, zsq, cnt, cands, idx,
                                               idxf_out);
  vq_gather_loss<<<N_ROWS / 16, 256, 0, stream>>>(z, e, idx, qout, partials);
  vq_finalize<<<1, 256, 0, stream>>>(partials, loss_out);
}